// Round 1
// baseline (3799.812 us; speedup 1.0000x reference)
//
#include <hip/hip_runtime.h>

#define CDIM 128
#define KOFF 4
#define TILE_I 64
#define EPS 1e-4f

// ---------------------------------------------------------------------------
// conv: for offset k, rows i0..i0+63:
//   Y[out_idx[k][i]] += (X[in_idx[k][i]] * mask[k][i]) @ W[k]
// One block = 64 rows x 128 cols tile. A-tile staged in LDS, W read via L1.
// ---------------------------------------------------------------------------
__global__ __launch_bounds__(256) void conv_tile_kernel(
    const float* __restrict__ X, const float* __restrict__ W,
    const int* __restrict__ in_idx, const int* __restrict__ out_idx,
    const int* __restrict__ mask, float* __restrict__ Y, int n)
{
    const int k  = blockIdx.y;
    const int i0 = blockIdx.x * TILE_I;
    const int t  = threadIdx.x;

    __shared__ float As[TILE_I][CDIM];
    __shared__ int   s_in[TILE_I];
    __shared__ int   s_out[TILE_I];
    __shared__ int   s_act[TILE_I];

    if (t < TILE_I) {
        int i = i0 + t;
        int act = 0, ii = 0, oi = 0;
        if (i < n) {
            size_t base = (size_t)k * n + i;
            int m = mask[base];
            ii = in_idx[base];
            oi = out_idx[base];
            act = (m != 0) ? 1 : 0;
        }
        s_act[t] = act;
        s_in[t]  = ii;
        s_out[t] = oi;
    }
    __syncthreads();

    // gather: thread t loads row r = t/4, quarter seg = t%4 (8 float4 each)
    {
        int r   = t >> 2;
        int seg = t & 3;
        float4* dst = (float4*)(&As[r][0]);
        if (s_act[r]) {
            const float4* src = (const float4*)(X + (size_t)s_in[r] * CDIM);
            #pragma unroll
            for (int u = 0; u < 8; ++u) dst[seg + 4 * u] = src[seg + 4 * u];
        } else {
            float4 z = make_float4(0.f, 0.f, 0.f, 0.f);
            #pragma unroll
            for (int u = 0; u < 8; ++u) dst[seg + 4 * u] = z;
        }
    }
    __syncthreads();

    // compute: thread (rt, ct) owns rows rt*8..rt*8+7, cols ct*4..ct*4+3
    const int rt = t >> 5;   // 0..7
    const int ct = t & 31;   // 0..31
    const int c0 = ct * 4;
    const float* __restrict__ Wk = W + (size_t)k * CDIM * CDIM + c0;

    float acc[8][4];
    #pragma unroll
    for (int r = 0; r < 8; ++r)
        #pragma unroll
        for (int c = 0; c < 4; ++c) acc[r][c] = 0.f;

    for (int j = 0; j < CDIM; j += 4) {
        float4 w0 = *(const float4*)(Wk + (size_t)(j + 0) * CDIM);
        float4 w1 = *(const float4*)(Wk + (size_t)(j + 1) * CDIM);
        float4 w2 = *(const float4*)(Wk + (size_t)(j + 2) * CDIM);
        float4 w3 = *(const float4*)(Wk + (size_t)(j + 3) * CDIM);
        #pragma unroll
        for (int rr = 0; rr < 8; ++rr) {
            float4 a = *(const float4*)(&As[rt * 8 + rr][j]);
            acc[rr][0] += a.x * w0.x; acc[rr][1] += a.x * w0.y;
            acc[rr][2] += a.x * w0.z; acc[rr][3] += a.x * w0.w;
            acc[rr][0] += a.y * w1.x; acc[rr][1] += a.y * w1.y;
            acc[rr][2] += a.y * w1.z; acc[rr][3] += a.y * w1.w;
            acc[rr][0] += a.z * w2.x; acc[rr][1] += a.z * w2.y;
            acc[rr][2] += a.z * w2.z; acc[rr][3] += a.z * w2.w;
            acc[rr][0] += a.w * w3.x; acc[rr][1] += a.w * w3.y;
            acc[rr][2] += a.w * w3.z; acc[rr][3] += a.w * w3.w;
        }
    }

    // scatter-add (skip masked rows)
    #pragma unroll
    for (int rr = 0; rr < 8; ++rr) {
        int r = rt * 8 + rr;
        if (s_act[r]) {
            float* yrow = Y + (size_t)s_out[r] * CDIM + c0;
            atomicAdd(yrow + 0, acc[rr][0]);
            atomicAdd(yrow + 1, acc[rr][1]);
            atomicAdd(yrow + 2, acc[rr][2]);
            atomicAdd(yrow + 3, acc[rr][3]);
        }
    }
}

// ---------------------------------------------------------------------------
// BN (+ optional ReLU) in-place, vectorized float4. total4 = n*C/4.
// ---------------------------------------------------------------------------
__global__ __launch_bounds__(256) void bn_relu_kernel(
    float* __restrict__ A,
    const float* __restrict__ gamma, const float* __restrict__ beta,
    const float* __restrict__ mean, const float* __restrict__ var,
    size_t total4)
{
    __shared__ float s_scale[CDIM], s_shift[CDIM];
    if (threadIdx.x < CDIM) {
        float sc = gamma[threadIdx.x] * rsqrtf(var[threadIdx.x] + EPS);
        s_scale[threadIdx.x] = sc;
        s_shift[threadIdx.x] = beta[threadIdx.x] - mean[threadIdx.x] * sc;
    }
    __syncthreads();
    size_t stride = (size_t)gridDim.x * blockDim.x;
    for (size_t idx = (size_t)blockIdx.x * blockDim.x + threadIdx.x;
         idx < total4; idx += stride) {
        float4 x = ((float4*)A)[idx];
        int c0 = ((int)(idx & 31)) * 4;   // C/4 = 32 float4 per row
        x.x = fmaxf(x.x * s_scale[c0 + 0] + s_shift[c0 + 0], 0.f);
        x.y = fmaxf(x.y * s_scale[c0 + 1] + s_shift[c0 + 1], 0.f);
        x.z = fmaxf(x.z * s_scale[c0 + 2] + s_shift[c0 + 2], 0.f);
        x.w = fmaxf(x.w * s_scale[c0 + 3] + s_shift[c0 + 3], 0.f);
        ((float4*)A)[idx] = x;
    }
}

__global__ __launch_bounds__(256) void bn_add_kernel(
    float* __restrict__ Y, const float* __restrict__ feat,
    const float* __restrict__ gamma, const float* __restrict__ beta,
    const float* __restrict__ mean, const float* __restrict__ var,
    size_t total4)
{
    __shared__ float s_scale[CDIM], s_shift[CDIM];
    if (threadIdx.x < CDIM) {
        float sc = gamma[threadIdx.x] * rsqrtf(var[threadIdx.x] + EPS);
        s_scale[threadIdx.x] = sc;
        s_shift[threadIdx.x] = beta[threadIdx.x] - mean[threadIdx.x] * sc;
    }
    __syncthreads();
    size_t stride = (size_t)gridDim.x * blockDim.x;
    for (size_t idx = (size_t)blockIdx.x * blockDim.x + threadIdx.x;
         idx < total4; idx += stride) {
        float4 x = ((float4*)Y)[idx];
        float4 f = ((const float4*)feat)[idx];
        int c0 = ((int)(idx & 31)) * 4;
        x.x = x.x * s_scale[c0 + 0] + s_shift[c0 + 0] + f.x;
        x.y = x.y * s_scale[c0 + 1] + s_shift[c0 + 1] + f.y;
        x.z = x.z * s_scale[c0 + 2] + s_shift[c0 + 2] + f.z;
        x.w = x.w * s_scale[c0 + 3] + s_shift[c0 + 3] + f.w;
        ((float4*)Y)[idx] = x;
    }
}

extern "C" void kernel_launch(void* const* d_in, const int* in_sizes, int n_in,
                              void* d_out, int out_size, void* d_ws, size_t ws_size,
                              hipStream_t stream)
{
    const float* feat   = (const float*)d_in[0];
    const float* W1     = (const float*)d_in[1];
    const float* W2     = (const float*)d_in[2];
    const float* gamma1 = (const float*)d_in[3];
    const float* beta1  = (const float*)d_in[4];
    const float* mean1  = (const float*)d_in[5];
    const float* var1   = (const float*)d_in[6];
    const float* gamma2 = (const float*)d_in[7];
    const float* beta2  = (const float*)d_in[8];
    const float* mean2  = (const float*)d_in[9];
    const float* var2   = (const float*)d_in[10];
    const int* in_idx   = (const int*)d_in[11];
    const int* out_idx  = (const int*)d_in[12];
    const int* mask     = (const int*)d_in[13];

    const int n = in_sizes[0] / CDIM;        // 500000
    const size_t nelem  = (size_t)n * CDIM;
    const size_t nbytes = nelem * sizeof(float);
    const size_t total4 = nelem / 4;

    float* h1  = (float*)d_ws;               // conv1 accumulator / h1 (256 MB)
    float* acc2 = (float*)d_out;             // conv2 accumulator -> final out

    const int tiles = (n + TILE_I - 1) / TILE_I;
    dim3 cgrid(tiles, KOFF);

    // conv1 -> h1
    hipMemsetAsync(h1, 0, nbytes, stream);
    conv_tile_kernel<<<cgrid, 256, 0, stream>>>(feat, W1, in_idx, out_idx, mask, h1, n);
    // bn1 + relu in place
    bn_relu_kernel<<<4096, 256, 0, stream>>>(h1, gamma1, beta1, mean1, var1, total4);
    // conv2 -> d_out
    hipMemsetAsync(acc2, 0, nbytes, stream);
    conv_tile_kernel<<<cgrid, 256, 0, stream>>>(h1, W2, in_idx, out_idx, mask, acc2, n);
    // bn2 + residual in place
    bn_add_kernel<<<4096, 256, 0, stream>>>(acc2, feat, gamma2, beta2, mean2, var2, total4);
}

// Round 2
// 1190.502 us; speedup vs baseline: 3.1918x; 3.1918x over previous
//
#include <hip/hip_runtime.h>

#define CDIM 128
#define KOFF 4
#define TILE_I 64
#define EPS 1e-4f

typedef __attribute__((ext_vector_type(8))) short bf16x8;
typedef __attribute__((ext_vector_type(4))) float f32x4;

__device__ __forceinline__ unsigned short f2bf(float f) {
    unsigned int u = __builtin_bit_cast(unsigned int, f);
    u += 0x7fffu + ((u >> 16) & 1u);          // round-to-nearest-even
    return (unsigned short)(u >> 16);
}

// ---------------------------------------------------------------------------
// W convert+transpose: Wt[k][cout][cin] = bf16(W[k][cin][cout]) for W1, W2
// ---------------------------------------------------------------------------
__global__ __launch_bounds__(256) void wconv_kernel(
    const float* __restrict__ W1, const float* __restrict__ W2,
    short* __restrict__ W1t, short* __restrict__ W2t)
{
    int idx = blockIdx.x * 256 + threadIdx.x;       // [k][co][ci], 65536 total
    if (idx >= KOFF * CDIM * CDIM) return;
    int ci = idx & (CDIM - 1);
    int co = (idx >> 7) & (CDIM - 1);
    int k  = idx >> 14;
    size_t src = (size_t)k * CDIM * CDIM + (size_t)ci * CDIM + co;
    W1t[idx] = (short)f2bf(W1[src]);
    W2t[idx] = (short)f2bf(W2[src]);
}

// ---------------------------------------------------------------------------
// MFMA conv: Y[out_idx[k][i]] += bf16(X[in_idx[k][i]] * mask) @ Wt[k]^T
// Block: 64 rows x 128 cols, one offset k. 4 waves, each a 16-row strip.
// ---------------------------------------------------------------------------
template <bool BF16IN>
__global__ __launch_bounds__(256) void conv_mfma_kernel(
    const void* __restrict__ Xv, const short* __restrict__ Wt,
    const int* __restrict__ in_idx, const int* __restrict__ out_idx,
    const int* __restrict__ mask, float* __restrict__ Y, int n)
{
    const int k  = blockIdx.y;
    const int i0 = blockIdx.x * TILE_I;
    const int t  = threadIdx.x;

    __shared__ alignas(16) short As[TILE_I * CDIM];   // 16 KB, swizzled
    __shared__ alignas(16) short Bs[CDIM * CDIM];     // 32 KB, swizzled
    __shared__ int s_out[TILE_I];
    __shared__ int s_act[TILE_I];

    if (t < TILE_I) {
        int i = i0 + t;
        int act = 0, oi = 0;
        if (i < n) {
            size_t base = (size_t)k * n + i;
            act = (mask[base] != 0) ? 1 : 0;
            oi  = out_idx[base];
        }
        s_act[t] = act;
        s_out[t] = oi;
    }
    // stage Wt[k] -> Bs (swizzled): 2048 chunks of 8 shorts
    {
        const short* Wk = Wt + (size_t)k * CDIM * CDIM;
        #pragma unroll
        for (int u = 0; u < 8; ++u) {
            int c   = u * 256 + t;          // chunk id
            int row = c >> 4;               // cout
            int cir = (c & 15) * 8;         // cin start
            int di  = row * CDIM + (cir ^ ((row & 7) << 3));
            *(uint4*)(&Bs[di]) = *(const uint4*)(&Wk[row * CDIM + cir]);
        }
    }
    __syncthreads();   // s_act/s_out ready (Bs consumed later, same barrier ok)

    // gather A rows -> As (bf16, swizzled). thread: row r = t>>2, seg = t&3
    {
        int r   = t >> 2;
        int seg = t & 3;
        int i   = i0 + r;
        int act = s_act[r];
        int ii  = act ? in_idx[(size_t)k * n + i] : 0;
        #pragma unroll
        for (int u = 0; u < 4; ++u) {
            int chunk = seg * 4 + u;            // 16 chunks of 8 shorts per row
            int ks    = chunk * 8;
            int di    = r * CDIM + (ks ^ ((r & 7) << 3));
            if (act) {
                if (BF16IN) {
                    const uint4* src = (const uint4*)((const short*)Xv + (size_t)ii * CDIM);
                    *(uint4*)(&As[di]) = src[chunk];
                } else {
                    const float4* src = (const float4*)((const float*)Xv + (size_t)ii * CDIM);
                    float4 f0 = src[chunk * 2], f1 = src[chunk * 2 + 1];
                    bf16x8 v;
                    v[0] = (short)f2bf(f0.x); v[1] = (short)f2bf(f0.y);
                    v[2] = (short)f2bf(f0.z); v[3] = (short)f2bf(f0.w);
                    v[4] = (short)f2bf(f1.x); v[5] = (short)f2bf(f1.y);
                    v[6] = (short)f2bf(f1.z); v[7] = (short)f2bf(f1.w);
                    *(bf16x8*)(&As[di]) = v;
                }
            } else {
                bf16x8 z = {0,0,0,0,0,0,0,0};
                *(bf16x8*)(&As[di]) = z;
            }
        }
    }
    __syncthreads();

    const int w    = t >> 6;     // wave 0..3: rows w*16..w*16+15
    const int lane = t & 63;
    const int lrow = lane & 15;
    const int lk   = (lane >> 4) * 8;    // k-offset within 32-wide step

    // A fragments for this wave's strip, all 4 K-steps
    bf16x8 af[4];
    {
        int row = w * 16 + lrow;
        #pragma unroll
        for (int kk = 0; kk < 4; ++kk) {
            int ks = kk * 32 + lk;
            af[kk] = *(const bf16x8*)(&As[row * CDIM + (ks ^ ((row & 7) << 3))]);
        }
    }

    f32x4 acc[8];
    #pragma unroll
    for (int nt = 0; nt < 8; ++nt) acc[nt] = (f32x4){0.f, 0.f, 0.f, 0.f};

    #pragma unroll
    for (int nt = 0; nt < 8; ++nt) {
        int brow = nt * 16 + lrow;       // cout
        #pragma unroll
        for (int kk = 0; kk < 4; ++kk) {
            int ks = kk * 32 + lk;
            bf16x8 bf = *(const bf16x8*)(&Bs[brow * CDIM + (ks ^ ((brow & 7) << 3))]);
            acc[nt] = __builtin_amdgcn_mfma_f32_16x16x32_bf16(af[kk], bf, acc[nt], 0, 0, 0);
        }
    }

    // scatter-add: lane covers rows (lane>>4)*4+j (j=0..3), col lane&15
    #pragma unroll
    for (int j = 0; j < 4; ++j) {
        int r = w * 16 + (lane >> 4) * 4 + j;
        if (s_act[r]) {
            float* yrow = Y + (size_t)s_out[r] * CDIM + lrow;
            #pragma unroll
            for (int nt = 0; nt < 8; ++nt)
                atomicAdd(yrow + nt * 16, acc[nt][j]);
        }
    }
}

// ---------------------------------------------------------------------------
// BN1 + ReLU + f32->bf16 convert: h1b = bf16(relu(bn(h1)))
// ---------------------------------------------------------------------------
__global__ __launch_bounds__(256) void bn_relu_cvt_kernel(
    const float* __restrict__ H, short* __restrict__ out,
    const float* __restrict__ gamma, const float* __restrict__ beta,
    const float* __restrict__ mean, const float* __restrict__ var,
    size_t total4)
{
    __shared__ float s_scale[CDIM], s_shift[CDIM];
    if (threadIdx.x < CDIM) {
        float sc = gamma[threadIdx.x] * rsqrtf(var[threadIdx.x] + EPS);
        s_scale[threadIdx.x] = sc;
        s_shift[threadIdx.x] = beta[threadIdx.x] - mean[threadIdx.x] * sc;
    }
    __syncthreads();
    size_t stride = (size_t)gridDim.x * blockDim.x;
    for (size_t idx = (size_t)blockIdx.x * blockDim.x + threadIdx.x;
         idx < total4; idx += stride) {
        float4 x = ((const float4*)H)[idx];
        int c0 = ((int)(idx & 31)) * 4;
        ushort4 o;
        o.x = f2bf(fmaxf(x.x * s_scale[c0 + 0] + s_shift[c0 + 0], 0.f));
        o.y = f2bf(fmaxf(x.y * s_scale[c0 + 1] + s_shift[c0 + 1], 0.f));
        o.z = f2bf(fmaxf(x.z * s_scale[c0 + 2] + s_shift[c0 + 2], 0.f));
        o.w = f2bf(fmaxf(x.w * s_scale[c0 + 3] + s_shift[c0 + 3], 0.f));
        ((ushort4*)out)[idx] = o;
    }
}

// ---------------------------------------------------------------------------
// BN2 + residual: out = bn(acc2) + feat
// ---------------------------------------------------------------------------
__global__ __launch_bounds__(256) void bn_add_kernel(
    const float* __restrict__ A, const float* __restrict__ feat,
    float* __restrict__ out,
    const float* __restrict__ gamma, const float* __restrict__ beta,
    const float* __restrict__ mean, const float* __restrict__ var,
    size_t total4)
{
    __shared__ float s_scale[CDIM], s_shift[CDIM];
    if (threadIdx.x < CDIM) {
        float sc = gamma[threadIdx.x] * rsqrtf(var[threadIdx.x] + EPS);
        s_scale[threadIdx.x] = sc;
        s_shift[threadIdx.x] = beta[threadIdx.x] - mean[threadIdx.x] * sc;
    }
    __syncthreads();
    size_t stride = (size_t)gridDim.x * blockDim.x;
    for (size_t idx = (size_t)blockIdx.x * blockDim.x + threadIdx.x;
         idx < total4; idx += stride) {
        float4 x = ((const float4*)A)[idx];
        float4 f = ((const float4*)feat)[idx];
        int c0 = ((int)(idx & 31)) * 4;
        x.x = x.x * s_scale[c0 + 0] + s_shift[c0 + 0] + f.x;
        x.y = x.y * s_scale[c0 + 1] + s_shift[c0 + 1] + f.y;
        x.z = x.z * s_scale[c0 + 2] + s_shift[c0 + 2] + f.z;
        x.w = x.w * s_scale[c0 + 3] + s_shift[c0 + 3] + f.w;
        ((float4*)out)[idx] = x;
    }
}

extern "C" void kernel_launch(void* const* d_in, const int* in_sizes, int n_in,
                              void* d_out, int out_size, void* d_ws, size_t ws_size,
                              hipStream_t stream)
{
    const float* feat   = (const float*)d_in[0];
    const float* W1     = (const float*)d_in[1];
    const float* W2     = (const float*)d_in[2];
    const float* gamma1 = (const float*)d_in[3];
    const float* beta1  = (const float*)d_in[4];
    const float* mean1  = (const float*)d_in[5];
    const float* var1   = (const float*)d_in[6];
    const float* gamma2 = (const float*)d_in[7];
    const float* beta2  = (const float*)d_in[8];
    const float* mean2  = (const float*)d_in[9];
    const float* var2   = (const float*)d_in[10];
    const int* in_idx   = (const int*)d_in[11];
    const int* out_idx  = (const int*)d_in[12];
    const int* mask     = (const int*)d_in[13];

    const int n = in_sizes[0] / CDIM;                 // 500000
    const size_t nelem  = (size_t)n * CDIM;
    const size_t nbytes = nelem * sizeof(float);      // 256 MB
    const size_t total4 = nelem / 4;

    // ws layout: [0, nbytes) f32 accumulator; then W1t, W2t (bf16)
    float* accf  = (float*)d_ws;
    short* W1t   = (short*)((char*)d_ws + nbytes);
    short* W2t   = W1t + (size_t)KOFF * CDIM * CDIM;
    // h1b (bf16) parks in d_out's space (dead by the time bn_add writes)
    short* h1b   = (short*)d_out;

    const int tiles = (n + TILE_I - 1) / TILE_I;
    dim3 cgrid(tiles, KOFF);

    // weights -> bf16 transposed
    wconv_kernel<<<(KOFF * CDIM * CDIM + 255) / 256, 256, 0, stream>>>(W1, W2, W1t, W2t);

    // conv1: feat(f32, converted in-kernel) @ W1 -> accf
    hipMemsetAsync(accf, 0, nbytes, stream);
    conv_mfma_kernel<false><<<cgrid, 256, 0, stream>>>(feat, W1t, in_idx, out_idx, mask, accf, n);

    // bn1 + relu + convert -> h1b (bf16)
    bn_relu_cvt_kernel<<<4096, 256, 0, stream>>>(accf, h1b, gamma1, beta1, mean1, var1, total4);

    // conv2: h1b(bf16) @ W2 -> accf (re-zeroed)
    hipMemsetAsync(accf, 0, nbytes, stream);
    conv_mfma_kernel<true><<<cgrid, 256, 0, stream>>>(h1b, W2t, in_idx, out_idx, mask, accf, n);

    // bn2 + residual -> d_out
    bn_add_kernel<<<4096, 256, 0, stream>>>(accf, feat, d_out ? (float*)d_out : nullptr,
                                            gamma2, beta2, mean2, var2, total4);
}